// Round 1
// baseline (233.001 us; speedup 1.0000x reference)
//
#include <hip/hip_runtime.h>
#include <math.h>

// Problem constants (fixed by reference): x [B=256, T=4096, C=32] f32,
// out [B, 64, 64, 32] f32, PAA_SIZE=64, seg=64, GAF_TYPE='GADF'.
#define BB   256
#define TT   4096
#define CC   32
#define PP   64      // paa_size
#define PSTR 36      // padded LDS row stride (floats): conflict-free lane-varying b128 reads

__device__ __forceinline__ float4 f4min(float4 a, float4 b) {
    return make_float4(fminf(a.x,b.x), fminf(a.y,b.y), fminf(a.z,b.z), fminf(a.w,b.w));
}
__device__ __forceinline__ float4 f4max(float4 a, float4 b) {
    return make_float4(fmaxf(a.x,b.x), fmaxf(a.y,b.y), fmaxf(a.z,b.z), fmaxf(a.w,b.w));
}
__device__ __forceinline__ void f4add(float4& a, float4 v) {
    a.x += v.x; a.y += v.y; a.z += v.z; a.w += v.w;
}
__device__ __forceinline__ float4 shflxor4(float4 v, int m) {
    return make_float4(__shfl_xor(v.x, m), __shfl_xor(v.y, m),
                       __shfl_xor(v.z, m), __shfl_xor(v.w, m));
}

__global__ __launch_bounds__(256) void gaf_kernel(const float* __restrict__ x,
                                                  float* __restrict__ out) {
    __shared__ float sp[PP * PSTR];       // p[64][36]
    __shared__ float sy[PP * PSTR];       // y[64][36]
    __shared__ float redmin[4 * CC];      // per-wave channel mins
    __shared__ float redmax[4 * CC];

    const int tid  = threadIdx.x;
    const int cg   = tid & 7;    // channel group: channels [4cg, 4cg+4)
    const int rb   = tid >> 3;   // 0..31: owns t in [rb*128, rb*128+128) = segments 2rb, 2rb+1
    const int wave = tid >> 6;
    const int lane = tid & 63;
    const int b    = blockIdx.x;

    // ---- Phase 1: single streaming pass — min/max + raw segment sums ----
    const float4* x4 = (const float4*)x + (size_t)b * (TT * CC / 4) + rb * 1024 + cg;

    const float FBIG = 3.402823466e+38f;
    float4 mn = make_float4(FBIG, FBIG, FBIG, FBIG);
    float4 mx = make_float4(-FBIG, -FBIG, -FBIG, -FBIG);
    float4 a0 = make_float4(0.f, 0.f, 0.f, 0.f);
    float4 a1 = make_float4(0.f, 0.f, 0.f, 0.f);

    #pragma unroll 8
    for (int k = 0; k < 64; ++k) {          // segment s = 2*rb
        float4 v = x4[k * 8];
        mn = f4min(mn, v); mx = f4max(mx, v); f4add(a0, v);
    }
    #pragma unroll 8
    for (int k = 64; k < 128; ++k) {        // segment s = 2*rb+1
        float4 v = x4[k * 8];
        mn = f4min(mn, v); mx = f4max(mx, v); f4add(a1, v);
    }

    // reduce min/max across rb within a wave (lanes stride 8 share cg)
    #pragma unroll
    for (int m = 8; m <= 32; m <<= 1) {
        mn = f4min(mn, shflxor4(mn, m));
        mx = f4max(mx, shflxor4(mx, m));
    }
    if (lane < 8) {
        *(float4*)&redmin[wave * CC + cg * 4] = mn;
        *(float4*)&redmax[wave * CC + cg * 4] = mx;
    }
    __syncthreads();

    float4 gmn = *(const float4*)&redmin[0 * CC + cg * 4];
    float4 gmx = *(const float4*)&redmax[0 * CC + cg * 4];
    #pragma unroll
    for (int w = 1; w < 4; ++w) {
        gmn = f4min(gmn, *(const float4*)&redmin[w * CC + cg * 4]);
        gmx = f4max(gmx, *(const float4*)&redmax[w * CC + cg * 4]);
    }

    float4 inv;
    inv.x = 1.0f / (gmx.x - gmn.x);
    inv.y = 1.0f / (gmx.y - gmn.y);
    inv.z = 1.0f / (gmx.z - gmn.z);
    inv.w = 1.0f / (gmx.w - gmn.w);

    // p = (segment_mean - min) * inv ; y = sqrt(1 - p^2)
    float4 p0, p1, y0, y1;
    const float s64 = 1.0f / 64.0f;
    p0.x = (a0.x * s64 - gmn.x) * inv.x;  p0.y = (a0.y * s64 - gmn.y) * inv.y;
    p0.z = (a0.z * s64 - gmn.z) * inv.z;  p0.w = (a0.w * s64 - gmn.w) * inv.w;
    p1.x = (a1.x * s64 - gmn.x) * inv.x;  p1.y = (a1.y * s64 - gmn.y) * inv.y;
    p1.z = (a1.z * s64 - gmn.z) * inv.z;  p1.w = (a1.w * s64 - gmn.w) * inv.w;
    y0.x = sqrtf(fmaxf(1.f - p0.x * p0.x, 0.f));  y0.y = sqrtf(fmaxf(1.f - p0.y * p0.y, 0.f));
    y0.z = sqrtf(fmaxf(1.f - p0.z * p0.z, 0.f));  y0.w = sqrtf(fmaxf(1.f - p0.w * p0.w, 0.f));
    y1.x = sqrtf(fmaxf(1.f - p1.x * p1.x, 0.f));  y1.y = sqrtf(fmaxf(1.f - p1.y * p1.y, 0.f));
    y1.z = sqrtf(fmaxf(1.f - p1.z * p1.z, 0.f));  y1.w = sqrtf(fmaxf(1.f - p1.w * p1.w, 0.f));

    *(float4*)&sp[(2 * rb)     * PSTR + cg * 4] = p0;
    *(float4*)&sp[(2 * rb + 1) * PSTR + cg * 4] = p1;
    *(float4*)&sy[(2 * rb)     * PSTR + cg * 4] = y0;
    *(float4*)&sy[(2 * rb + 1) * PSTR + cg * 4] = y1;
    __syncthreads();

    // ---- Phase 2: out[b,i,j,c] = y_i*p_j - p_i*y_j ----
    // Thread owns j1 = rb, j2 = rb+32, channels [4cg,4cg+4). Hoist p_j/y_j.
    const int j1 = rb, j2 = rb + 32;
    const float4 pj1 = *(const float4*)&sp[j1 * PSTR + cg * 4];
    const float4 yj1 = *(const float4*)&sy[j1 * PSTR + cg * 4];
    const float4 pj2 = *(const float4*)&sp[j2 * PSTR + cg * 4];
    const float4 yj2 = *(const float4*)&sy[j2 * PSTR + cg * 4];

    float4* o4 = (float4*)out + (size_t)b * (PP * PP * CC / 4);

    #pragma unroll 4
    for (int i = 0; i < PP; ++i) {
        const float4 pi = *(const float4*)&sp[i * PSTR + cg * 4];
        const float4 yi = *(const float4*)&sy[i * PSTR + cg * 4];
        float4 r1, r2;
        r1.x = yi.x * pj1.x - pi.x * yj1.x;  r1.y = yi.y * pj1.y - pi.y * yj1.y;
        r1.z = yi.z * pj1.z - pi.z * yj1.z;  r1.w = yi.w * pj1.w - pi.w * yj1.w;
        r2.x = yi.x * pj2.x - pi.x * yj2.x;  r2.y = yi.y * pj2.y - pi.y * yj2.y;
        r2.z = yi.z * pj2.z - pi.z * yj2.z;  r2.w = yi.w * pj2.w - pi.w * yj2.w;
        o4[i * 512 + j1 * 8 + cg] = r1;
        o4[i * 512 + j2 * 8 + cg] = r2;
    }
}

extern "C" void kernel_launch(void* const* d_in, const int* in_sizes, int n_in,
                              void* d_out, int out_size, void* d_ws, size_t ws_size,
                              hipStream_t stream) {
    const float* x = (const float*)d_in[0];
    float* out = (float*)d_out;
    gaf_kernel<<<BB, 256, 0, stream>>>(x, out);
}